// Round 2
// baseline (7973.096 us; speedup 1.0000x reference)
//
#include <hip/hip_runtime.h>
#include <math.h>

#define NATOM 50000
#define NEDGE 800000
#define NGRAPH 256
#define HD 128
#define NL 4
#define AFD 108
#define EFD 41
#define GFD 239
#define TOUT 5
#define LNEPS 1e-5f

__device__ __forceinline__ float silu_f(float v) { return v / (1.f + __expf(-v)); }

// ---------------- CSR build: histogram of dst ----------------
__global__ void hist_kernel(const int* __restrict__ dst, int* __restrict__ count) {
    for (int e = blockIdx.x * blockDim.x + threadIdx.x; e < NEDGE; e += gridDim.x * blockDim.x)
        atomicAdd(&count[dst[e]], 1);
}

// single-block exclusive scan over 50000 counts -> rowptr / cursor
__global__ void scan_kernel(const int* __restrict__ count, int* __restrict__ rowptr,
                            int* __restrict__ cursor) {
    __shared__ int s_w[4];
    __shared__ int s_carry;
    const int t = threadIdx.x, lane = t & 63, wv = t >> 6;
    if (t == 0) { s_carry = 0; rowptr[0] = 0; }
    __syncthreads();
    for (int base = 0; base < NATOM; base += 256) {
        int v = (base + t < NATOM) ? count[base + t] : 0;
        int x = v;
#pragma unroll
        for (int off = 1; off < 64; off <<= 1) {
            int y = __shfl_up(x, off);
            if (lane >= off) x += y;
        }
        if (lane == 63) s_w[wv] = x;
        __syncthreads();
        int wvoff = s_carry;
        for (int w = 0; w < wv; w++) wvoff += s_w[w];
        int incl = x + wvoff;
        if (base + t < NATOM) { rowptr[base + t + 1] = incl; cursor[base + t] = incl - v; }
        __syncthreads();
        if (t == 255) s_carry = incl;
        __syncthreads();
    }
}

// scatter: permutation position of each edge in dst-sorted order
__global__ void scatter_kernel(const int* __restrict__ dst, int* __restrict__ cursor,
                               int* __restrict__ eidp) {
    for (int e = blockIdx.x * blockDim.x + threadIdx.x; e < NEDGE; e += gridDim.x * blockDim.x) {
        int d = dst[e];
        int p = atomicAdd(&cursor[d], 1);
        eidp[p] = e;
    }
}

// ---------------- atom embedding: h = silu(x@w1+b1)@w2 + b2 ----------------
__global__ __launch_bounds__(256, 2) void atom_kernel(
    const float* __restrict__ x, const float* __restrict__ w1, const float* __restrict__ b1,
    const float* __restrict__ w2, const float* __restrict__ b2, float* __restrict__ h)
{
    __shared__ float s_x[64 * AFD];
    __shared__ float s_hid[64 * HD];
    const int t = threadIdx.x, cg = t & 31, rg = t >> 5, c4 = cg * 4;
    const int r0 = blockIdx.x * 64;

    for (int i = t; i < 64 * AFD; i += 256) {
        size_t g = (size_t)r0 * AFD + i;
        s_x[i] = (g < (size_t)NATOM * AFD) ? x[g] : 0.f;
    }
    float4 bb1 = *(const float4*)&b1[c4];
    float4 bb2 = *(const float4*)&b2[c4];
    __syncthreads();

    float4 acc[8];
#pragma unroll
    for (int i = 0; i < 8; i++) acc[i] = bb1;
    for (int k = 0; k < AFD; k++) {
        float4 w = *(const float4*)&w1[k * HD + c4];
#pragma unroll
        for (int i = 0; i < 8; i++) {
            float a = s_x[(rg * 8 + i) * AFD + k];
            acc[i].x += a * w.x; acc[i].y += a * w.y; acc[i].z += a * w.z; acc[i].w += a * w.w;
        }
    }
#pragma unroll
    for (int i = 0; i < 8; i++) {
        float4 v = acc[i];
        v.x = silu_f(v.x); v.y = silu_f(v.y); v.z = silu_f(v.z); v.w = silu_f(v.w);
        *(float4*)&s_hid[(rg * 8 + i) * HD + c4] = v;
    }
    __syncthreads();

    float4 o[8];
#pragma unroll
    for (int i = 0; i < 8; i++) o[i] = bb2;
    for (int j = 0; j < HD; j++) {
        float4 w = *(const float4*)&w2[j * HD + c4];
#pragma unroll
        for (int i = 0; i < 8; i++) {
            float a = s_hid[(rg * 8 + i) * HD + j];
            o[i].x += a * w.x; o[i].y += a * w.y; o[i].z += a * w.z; o[i].w += a * w.w;
        }
    }
#pragma unroll
    for (int i = 0; i < 8; i++) {
        int r = r0 + rg * 8 + i;
        if (r < NATOM) *(float4*)&h[(size_t)r * HD + c4] = o[i];
    }
}

// -------- edge kernel over dst-sorted edge positions --------
// Wf = silu(ea@ew1+b1)@ew2+b2; msg = h[src]*Wf; atomic agg[dst] += msg (dst-local now)
__global__ __launch_bounds__(256, 3) void edge_kernel(
    const float* __restrict__ edge_attr,
    const float* __restrict__ w1, const float* __restrict__ b1,
    const float* __restrict__ w2, const float* __restrict__ b2,
    const int* __restrict__ eidp, const int* __restrict__ src, const int* __restrict__ dst,
    const float* __restrict__ h, float* __restrict__ agg)
{
    __shared__ float s_ea[64 * EFD];   // 10496 B
    __shared__ float s_hid[64 * HD];   // 32768 B
    __shared__ int s_eid[64];
    __shared__ int s_src[64];
    __shared__ int s_dst[64];

    const int t = threadIdx.x, cg = t & 31, rg = t >> 5, c4 = cg * 4;
    const int wv = t >> 6, lane = t & 63;

    float4 bb1 = *(const float4*)&b1[c4];
    float4 bb2 = *(const float4*)&b2[c4];

    const int ntiles = NEDGE / 64;
    for (int tile = blockIdx.x; tile < ntiles; tile += gridDim.x) {
        const int p0 = tile * 64;
        if (t < 64) {
            int e = eidp[p0 + t];
            s_eid[t] = e;
            s_src[t] = src[e];
            s_dst[t] = dst[e];
        }
        __syncthreads();
        // gather edge_attr rows (each wave: 16 edges, lanes 0..40 load one float)
#pragma unroll 4
        for (int i = 0; i < 16; i++) {
            int e = s_eid[wv * 16 + i];
            if (lane < EFD) s_ea[(wv * 16 + i) * EFD + lane] = edge_attr[(size_t)e * EFD + lane];
        }
        __syncthreads();

        // GEMM1: [64,41] @ [41,128], w1 streamed from L1/L2
        float4 acc[8];
#pragma unroll
        for (int i = 0; i < 8; i++) acc[i] = bb1;
        for (int k = 0; k < EFD; k++) {
            float4 w = *(const float4*)&w1[k * HD + c4];
#pragma unroll
            for (int i = 0; i < 8; i++) {
                float a = s_ea[(rg * 8 + i) * EFD + k];
                acc[i].x += a * w.x; acc[i].y += a * w.y; acc[i].z += a * w.z; acc[i].w += a * w.w;
            }
        }
#pragma unroll
        for (int i = 0; i < 8; i++) {
            float4 v = acc[i];
            v.x = silu_f(v.x); v.y = silu_f(v.y); v.z = silu_f(v.z); v.w = silu_f(v.w);
            *(float4*)&s_hid[(rg * 8 + i) * HD + c4] = v;
        }
        __syncthreads();

        // GEMM2: [64,128] @ [128,128], w2 from L2
        float4 o[8];
#pragma unroll
        for (int i = 0; i < 8; i++) o[i] = bb2;
        for (int j = 0; j < HD; j++) {
            float4 w = *(const float4*)&w2[j * HD + c4];
#pragma unroll
            for (int i = 0; i < 8; i++) {
                float a = s_hid[(rg * 8 + i) * HD + j];
                o[i].x += a * w.x; o[i].y += a * w.y; o[i].z += a * w.z; o[i].w += a * w.w;
            }
        }
        // gather h[src], multiply, scatter-add to agg[dst] (dst nearly sorted -> L2-local)
#pragma unroll
        for (int i = 0; i < 8; i++) {
            int e = rg * 8 + i;
            int si = s_src[e], di = s_dst[e];
            float4 hs = *(const float4*)&h[(size_t)si * HD + c4];
            float mx = o[i].x * hs.x, my = o[i].y * hs.y, mz = o[i].z * hs.z, mw = o[i].w * hs.w;
            float* ap = agg + (size_t)di * HD + c4;
            atomicAdd(ap + 0, mx);
            atomicAdd(ap + 1, my);
            atomicAdd(ap + 2, mz);
            atomicAdd(ap + 3, mw);
        }
        __syncthreads();
    }
}

// -------- node kernel: out = silu(agg@w1+b1)@w2+b2; h = LN(h+out)*g+b ----------
__global__ __launch_bounds__(256, 2) void node_kernel(
    const float* __restrict__ agg,
    const float* __restrict__ w1, const float* __restrict__ b1,
    const float* __restrict__ w2, const float* __restrict__ b2,
    const float* __restrict__ lg, const float* __restrict__ lb,
    float* __restrict__ h)
{
    __shared__ float s_in[64 * HD];
    __shared__ float s_hid[64 * HD];
    const int t = threadIdx.x, cg = t & 31, rg = t >> 5, c4 = cg * 4;
    const int r0 = blockIdx.x * 64;

    for (int i = t; i < 64 * HD; i += 256) {
        size_t g = (size_t)r0 * HD + i;
        s_in[i] = (g < (size_t)NATOM * HD) ? agg[g] : 0.f;
    }
    float4 bb1 = *(const float4*)&b1[c4];
    float4 bb2 = *(const float4*)&b2[c4];
    float4 g4 = *(const float4*)&lg[c4];
    float4 lb4 = *(const float4*)&lb[c4];
    __syncthreads();

    float4 acc[8];
#pragma unroll
    for (int i = 0; i < 8; i++) acc[i] = bb1;
    for (int k = 0; k < HD; k++) {
        float4 w = *(const float4*)&w1[k * HD + c4];
#pragma unroll
        for (int i = 0; i < 8; i++) {
            float a = s_in[(rg * 8 + i) * HD + k];
            acc[i].x += a * w.x; acc[i].y += a * w.y; acc[i].z += a * w.z; acc[i].w += a * w.w;
        }
    }
#pragma unroll
    for (int i = 0; i < 8; i++) {
        float4 v = acc[i];
        v.x = silu_f(v.x); v.y = silu_f(v.y); v.z = silu_f(v.z); v.w = silu_f(v.w);
        *(float4*)&s_hid[(rg * 8 + i) * HD + c4] = v;
    }
    __syncthreads();

    float4 o[8];
#pragma unroll
    for (int i = 0; i < 8; i++) o[i] = bb2;
    for (int j = 0; j < HD; j++) {
        float4 w = *(const float4*)&w2[j * HD + c4];
#pragma unroll
        for (int i = 0; i < 8; i++) {
            float a = s_hid[(rg * 8 + i) * HD + j];
            o[i].x += a * w.x; o[i].y += a * w.y; o[i].z += a * w.z; o[i].w += a * w.w;
        }
    }
#pragma unroll
    for (int i = 0; i < 8; i++) {
        int r = r0 + rg * 8 + i;
        float4 hv = make_float4(0.f, 0.f, 0.f, 0.f);
        if (r < NATOM) hv = *(const float4*)&h[(size_t)r * HD + c4];
        float4 v;
        v.x = hv.x + o[i].x; v.y = hv.y + o[i].y; v.z = hv.z + o[i].z; v.w = hv.w + o[i].w;
        float s1 = v.x + v.y + v.z + v.w;
        float s2 = v.x * v.x + v.y * v.y + v.z * v.z + v.w * v.w;
#pragma unroll
        for (int off = 16; off >= 1; off >>= 1) {
            s1 += __shfl_xor(s1, off);
            s2 += __shfl_xor(s2, off);
        }
        float mean = s1 * (1.f / HD);
        float var = s2 * (1.f / HD) - mean * mean;
        float rstd = rsqrtf(var + LNEPS);
        float4 y;
        y.x = (v.x - mean) * rstd * g4.x + lb4.x;
        y.y = (v.y - mean) * rstd * g4.y + lb4.y;
        y.z = (v.z - mean) * rstd * g4.z + lb4.z;
        y.w = (v.w - mean) * rstd * g4.w + lb4.w;
        if (r < NATOM) *(float4*)&h[(size_t)r * HD + c4] = y;
    }
}

// -------- pool + head: one block per graph ----------
__global__ __launch_bounds__(128) void head_kernel(
    const float* __restrict__ h, const float* __restrict__ gfeat,
    const float* __restrict__ gw, const float* __restrict__ gb,
    const float* __restrict__ ow1, const float* __restrict__ ob1,
    const float* __restrict__ ow2, const float* __restrict__ ob2,
    const float* __restrict__ ow3, const float* __restrict__ ob3,
    const int* __restrict__ batch, float* __restrict__ out)
{
    __shared__ float comb[2 * HD];
    __shared__ float h1[HD];
    __shared__ float h2[64];
    const int b = blockIdx.x;
    const int c = threadIdx.x;

    int lo = 0, hi = NATOM;
    while (lo < hi) { int m = (lo + hi) >> 1; if (batch[m] < b) lo = m + 1; else hi = m; }
    const int start = lo;
    hi = NATOM;
    while (lo < hi) { int m = (lo + hi) >> 1; if (batch[m] < b + 1) lo = m + 1; else hi = m; }
    const int end = lo;

    float s = 0.f;
    for (int r = start; r < end; r++) s += h[(size_t)r * HD + c];
    float cnt = (float)(end - start);
    if (cnt < 1.f) cnt = 1.f;
    comb[c] = s / cnt;

    float a = gb[c];
    for (int k = 0; k < GFD; k++) a += gfeat[b * GFD + k] * gw[k * HD + c];
    comb[HD + c] = silu_f(a);
    __syncthreads();

    float u = ob1[c];
    for (int j = 0; j < 2 * HD; j++) u += comb[j] * ow1[j * HD + c];
    h1[c] = silu_f(u);
    __syncthreads();

    if (c < 64) {
        float v = ob2[c];
        for (int j = 0; j < HD; j++) v += h1[j] * ow2[j * 64 + c];
        h2[c] = silu_f(v);
    }
    __syncthreads();

    if (c < TOUT) {
        float v = ob3[c];
        for (int j = 0; j < 64; j++) v += h2[j] * ow3[j * TOUT + c];
        out[b * TOUT + c] = v;
    }
}

extern "C" void kernel_launch(void* const* d_in, const int* in_sizes, int n_in,
                              void* d_out, int out_size, void* d_ws, size_t ws_size,
                              hipStream_t stream) {
    const float* x        = (const float*)d_in[0];
    const float* edge_attr= (const float*)d_in[1];
    const float* gfeat    = (const float*)d_in[2];
    const float* ae_w1    = (const float*)d_in[3];
    const float* ae_b1    = (const float*)d_in[4];
    const float* ae_w2    = (const float*)d_in[5];
    const float* ae_b2    = (const float*)d_in[6];
    const float* ew1      = (const float*)d_in[7];
    const float* eb1      = (const float*)d_in[8];
    const float* ew2      = (const float*)d_in[9];
    const float* eb2      = (const float*)d_in[10];
    const float* nw1      = (const float*)d_in[11];
    const float* nb1      = (const float*)d_in[12];
    const float* nw2      = (const float*)d_in[13];
    const float* nb2      = (const float*)d_in[14];
    const float* ln_g     = (const float*)d_in[15];
    const float* ln_b     = (const float*)d_in[16];
    const float* gw       = (const float*)d_in[17];
    const float* gb       = (const float*)d_in[18];
    const float* ow1      = (const float*)d_in[19];
    const float* ob1      = (const float*)d_in[20];
    const float* ow2      = (const float*)d_in[21];
    const float* ob2      = (const float*)d_in[22];
    const float* ow3      = (const float*)d_in[23];
    const float* ob3      = (const float*)d_in[24];
    const int* edge_index = (const int*)d_in[25];
    const int* batch      = (const int*)d_in[26];

    float* h    = (float*)d_ws;                      // NATOM*HD
    float* agg  = h + (size_t)NATOM * HD;            // NATOM*HD
    int* count  = (int*)(agg + (size_t)NATOM * HD);  // NATOM
    int* rowptr = count + NATOM;                     // NATOM+1
    int* cursor = rowptr + NATOM + 1;                // NATOM
    int* eidp   = cursor + NATOM;                    // NEDGE

    const int* src = edge_index;
    const int* dst = edge_index + NEDGE;

    const int row_blocks = (NATOM + 63) / 64;  // 782

    // ---- per-launch counting sort of edges by dst ----
    hipMemsetAsync(count, 0, NATOM * sizeof(int), stream);
    hist_kernel<<<1024, 256, 0, stream>>>(dst, count);
    scan_kernel<<<1, 256, 0, stream>>>(count, rowptr, cursor);
    scatter_kernel<<<1024, 256, 0, stream>>>(dst, cursor, eidp);

    atom_kernel<<<row_blocks, 256, 0, stream>>>(x, ae_w1, ae_b1, ae_w2, ae_b2, h);

    for (int l = 0; l < NL; l++) {
        hipMemsetAsync(agg, 0, (size_t)NATOM * HD * sizeof(float), stream);
        edge_kernel<<<2048, 256, 0, stream>>>(
            edge_attr,
            ew1 + (size_t)l * EFD * HD, eb1 + (size_t)l * HD,
            ew2 + (size_t)l * HD * HD,  eb2 + (size_t)l * HD,
            eidp, src, dst, h, agg);
        node_kernel<<<row_blocks, 256, 0, stream>>>(
            agg,
            nw1 + (size_t)l * HD * HD, nb1 + (size_t)l * HD,
            nw2 + (size_t)l * HD * HD, nb2 + (size_t)l * HD,
            ln_g + (size_t)l * HD, ln_b + (size_t)l * HD,
            h);
    }

    head_kernel<<<NGRAPH, 128, 0, stream>>>(
        h, gfeat, gw, gb, ow1, ob1, ow2, ob2, ow3, ob3, batch, (float*)d_out);
}

// Round 3
// 3619.377 us; speedup vs baseline: 2.2029x; 2.2029x over previous
//
#include <hip/hip_runtime.h>
#include <math.h>

#define NATOM 50000
#define NEDGE 800000
#define NGRAPH 256
#define HD 128
#define NL 4
#define AFD 108
#define EFD 41
#define GFD 239
#define TOUT 5
#define LNEPS 1e-5f

__device__ __forceinline__ float silu_f(float v) { return v / (1.f + __expf(-v)); }

// ---------------- CSR build: histogram of dst ----------------
__global__ void hist_kernel(const int* __restrict__ dst, int* __restrict__ count) {
    for (int e = blockIdx.x * blockDim.x + threadIdx.x; e < NEDGE; e += gridDim.x * blockDim.x)
        atomicAdd(&count[dst[e]], 1);
}

// single-block exclusive scan over 50000 counts -> rowptr / cursor
__global__ void scan_kernel(const int* __restrict__ count, int* __restrict__ rowptr,
                            int* __restrict__ cursor) {
    __shared__ int s_w[4];
    __shared__ int s_carry;
    const int t = threadIdx.x, lane = t & 63, wv = t >> 6;
    if (t == 0) { s_carry = 0; rowptr[0] = 0; }
    __syncthreads();
    for (int base = 0; base < NATOM; base += 256) {
        int v = (base + t < NATOM) ? count[base + t] : 0;
        int x = v;
#pragma unroll
        for (int off = 1; off < 64; off <<= 1) {
            int y = __shfl_up(x, off);
            if (lane >= off) x += y;
        }
        if (lane == 63) s_w[wv] = x;
        __syncthreads();
        int wvoff = s_carry;
        for (int w = 0; w < wv; w++) wvoff += s_w[w];
        int incl = x + wvoff;
        if (base + t < NATOM) { rowptr[base + t + 1] = incl; cursor[base + t] = incl - v; }
        __syncthreads();
        if (t == 255) s_carry = incl;
        __syncthreads();
    }
}

// pos[e] = position of edge e in dst-sorted order
__global__ void pos_kernel(const int* __restrict__ dst, int* __restrict__ cursor,
                           int* __restrict__ pos) {
    for (int e = blockIdx.x * blockDim.x + threadIdx.x; e < NEDGE; e += gridDim.x * blockDim.x) {
        int d = dst[e];
        pos[e] = atomicAdd(&cursor[d], 1);
    }
}

// ---------------- atom embedding: h = silu(x@w1+b1)@w2 + b2 ----------------
__global__ __launch_bounds__(256, 2) void atom_kernel(
    const float* __restrict__ x, const float* __restrict__ w1, const float* __restrict__ b1,
    const float* __restrict__ w2, const float* __restrict__ b2, float* __restrict__ h)
{
    __shared__ float s_x[64 * AFD];
    __shared__ float s_hid[64 * HD];
    const int t = threadIdx.x, cg = t & 31, rg = t >> 5, c4 = cg * 4;
    const int r0 = blockIdx.x * 64;

    for (int i = t; i < 64 * AFD; i += 256) {
        size_t g = (size_t)r0 * AFD + i;
        s_x[i] = (g < (size_t)NATOM * AFD) ? x[g] : 0.f;
    }
    float4 bb1 = *(const float4*)&b1[c4];
    float4 bb2 = *(const float4*)&b2[c4];
    __syncthreads();

    float4 acc[8];
#pragma unroll
    for (int i = 0; i < 8; i++) acc[i] = bb1;
    for (int k = 0; k < AFD; k++) {
        float4 w = *(const float4*)&w1[k * HD + c4];
#pragma unroll
        for (int i = 0; i < 8; i++) {
            float a = s_x[(rg * 8 + i) * AFD + k];
            acc[i].x += a * w.x; acc[i].y += a * w.y; acc[i].z += a * w.z; acc[i].w += a * w.w;
        }
    }
#pragma unroll
    for (int i = 0; i < 8; i++) {
        float4 v = acc[i];
        v.x = silu_f(v.x); v.y = silu_f(v.y); v.z = silu_f(v.z); v.w = silu_f(v.w);
        *(float4*)&s_hid[(rg * 8 + i) * HD + c4] = v;
    }
    __syncthreads();

    float4 o[8];
#pragma unroll
    for (int i = 0; i < 8; i++) o[i] = bb2;
    for (int j = 0; j < HD; j++) {
        float4 w = *(const float4*)&w2[j * HD + c4];
#pragma unroll
        for (int i = 0; i < 8; i++) {
            float a = s_hid[(rg * 8 + i) * HD + j];
            o[i].x += a * w.x; o[i].y += a * w.y; o[i].z += a * w.z; o[i].w += a * w.w;
        }
    }
#pragma unroll
    for (int i = 0; i < 8; i++) {
        int r = r0 + rg * 8 + i;
        if (r < NATOM) *(float4*)&h[(size_t)r * HD + c4] = o[i];
    }
}

// -------- edge kernel (primary): streaming edge order, msg written to sorted position --------
__global__ __launch_bounds__(256, 3) void edge_kernel_msg(
    const float* __restrict__ edge_attr,
    const float* __restrict__ w1, const float* __restrict__ b1,
    const float* __restrict__ w2, const float* __restrict__ b2,
    const int* __restrict__ src, const int* __restrict__ pos,
    const float* __restrict__ h, float* __restrict__ msg)
{
    __shared__ float s_ea[64 * EFD];   // 10496 B
    __shared__ float s_hid[64 * HD];   // 32768 B
    __shared__ int s_pos[64];
    __shared__ int s_src[64];

    const int t = threadIdx.x, cg = t & 31, rg = t >> 5, c4 = cg * 4;

    float4 bb1 = *(const float4*)&b1[c4];
    float4 bb2 = *(const float4*)&b2[c4];

    const int ntiles = NEDGE / 64;
    for (int tile = blockIdx.x; tile < ntiles; tile += gridDim.x) {
        const int e0 = tile * 64;
        for (int i = t; i < 64 * EFD; i += 256) s_ea[i] = edge_attr[(size_t)e0 * EFD + i];
        if (t < 64) { s_pos[t] = pos[e0 + t]; s_src[t] = src[e0 + t]; }
        __syncthreads();

        // GEMM1: [64,41] @ [41,128]
        float4 acc[8];
#pragma unroll
        for (int i = 0; i < 8; i++) acc[i] = bb1;
        for (int k = 0; k < EFD; k++) {
            float4 w = *(const float4*)&w1[k * HD + c4];
#pragma unroll
            for (int i = 0; i < 8; i++) {
                float a = s_ea[(rg * 8 + i) * EFD + k];
                acc[i].x += a * w.x; acc[i].y += a * w.y; acc[i].z += a * w.z; acc[i].w += a * w.w;
            }
        }
#pragma unroll
        for (int i = 0; i < 8; i++) {
            float4 v = acc[i];
            v.x = silu_f(v.x); v.y = silu_f(v.y); v.z = silu_f(v.z); v.w = silu_f(v.w);
            *(float4*)&s_hid[(rg * 8 + i) * HD + c4] = v;
        }
        __syncthreads();

        // GEMM2: [64,128] @ [128,128]
        float4 o[8];
#pragma unroll
        for (int i = 0; i < 8; i++) o[i] = bb2;
        for (int j = 0; j < HD; j++) {
            float4 w = *(const float4*)&w2[j * HD + c4];
#pragma unroll
            for (int i = 0; i < 8; i++) {
                float a = s_hid[(rg * 8 + i) * HD + j];
                o[i].x += a * w.x; o[i].y += a * w.y; o[i].z += a * w.z; o[i].w += a * w.w;
            }
        }
        // msg = Wf * h[src], stored at dst-sorted position (no atomics)
#pragma unroll
        for (int i = 0; i < 8; i++) {
            int e = rg * 8 + i;
            int si = s_src[e], p = s_pos[e];
            float4 hs = *(const float4*)&h[(size_t)si * HD + c4];
            float4 m;
            m.x = o[i].x * hs.x; m.y = o[i].y * hs.y; m.z = o[i].z * hs.z; m.w = o[i].w * hs.w;
            *(float4*)&msg[(size_t)p * HD + c4] = m;
        }
        __syncthreads();
    }
}

// -------- node kernel (primary): CSR-gather msg -> agg; MLP; residual+LN --------
__global__ __launch_bounds__(256, 2) void node_kernel_csr(
    const float* __restrict__ msg, const int* __restrict__ rowptr,
    const float* __restrict__ w1, const float* __restrict__ b1,
    const float* __restrict__ w2, const float* __restrict__ b2,
    const float* __restrict__ lg, const float* __restrict__ lb,
    float* __restrict__ h)
{
    __shared__ float s_in[64 * HD];
    __shared__ float s_hid[64 * HD];
    __shared__ int s_rp[65];
    const int t = threadIdx.x, cg = t & 31, rg = t >> 5, c4 = cg * 4;
    const int r0 = blockIdx.x * 64;

    if (t < 65) {
        int idx = r0 + t;
        if (idx > NATOM) idx = NATOM;
        s_rp[t] = rowptr[idx];
    }
    float4 bb1 = *(const float4*)&b1[c4];
    float4 bb2 = *(const float4*)&b2[c4];
    float4 g4 = *(const float4*)&lg[c4];
    float4 lb4 = *(const float4*)&lb[c4];
    __syncthreads();

    // gather + sum messages for 8 nodes (consecutive msg rows per node)
#pragma unroll
    for (int i = 0; i < 8; i++) {
        int rr = rg * 8 + i;
        int beg = s_rp[rr], end = s_rp[rr + 1];
        float4 a0 = make_float4(0.f, 0.f, 0.f, 0.f);
        float4 a1 = make_float4(0.f, 0.f, 0.f, 0.f);
        int p = beg;
        for (; p + 1 < end; p += 2) {
            float4 m0 = *(const float4*)&msg[(size_t)p * HD + c4];
            float4 m1 = *(const float4*)&msg[(size_t)(p + 1) * HD + c4];
            a0.x += m0.x; a0.y += m0.y; a0.z += m0.z; a0.w += m0.w;
            a1.x += m1.x; a1.y += m1.y; a1.z += m1.z; a1.w += m1.w;
        }
        if (p < end) {
            float4 m0 = *(const float4*)&msg[(size_t)p * HD + c4];
            a0.x += m0.x; a0.y += m0.y; a0.z += m0.z; a0.w += m0.w;
        }
        a0.x += a1.x; a0.y += a1.y; a0.z += a1.z; a0.w += a1.w;
        *(float4*)&s_in[rr * HD + c4] = a0;
    }
    __syncthreads();

    float4 acc[8];
#pragma unroll
    for (int i = 0; i < 8; i++) acc[i] = bb1;
    for (int k = 0; k < HD; k++) {
        float4 w = *(const float4*)&w1[k * HD + c4];
#pragma unroll
        for (int i = 0; i < 8; i++) {
            float a = s_in[(rg * 8 + i) * HD + k];
            acc[i].x += a * w.x; acc[i].y += a * w.y; acc[i].z += a * w.z; acc[i].w += a * w.w;
        }
    }
#pragma unroll
    for (int i = 0; i < 8; i++) {
        float4 v = acc[i];
        v.x = silu_f(v.x); v.y = silu_f(v.y); v.z = silu_f(v.z); v.w = silu_f(v.w);
        *(float4*)&s_hid[(rg * 8 + i) * HD + c4] = v;
    }
    __syncthreads();

    float4 o[8];
#pragma unroll
    for (int i = 0; i < 8; i++) o[i] = bb2;
    for (int j = 0; j < HD; j++) {
        float4 w = *(const float4*)&w2[j * HD + c4];
#pragma unroll
        for (int i = 0; i < 8; i++) {
            float a = s_hid[(rg * 8 + i) * HD + j];
            o[i].x += a * w.x; o[i].y += a * w.y; o[i].z += a * w.z; o[i].w += a * w.w;
        }
    }
#pragma unroll
    for (int i = 0; i < 8; i++) {
        int r = r0 + rg * 8 + i;
        float4 hv = make_float4(0.f, 0.f, 0.f, 0.f);
        if (r < NATOM) hv = *(const float4*)&h[(size_t)r * HD + c4];
        float4 v;
        v.x = hv.x + o[i].x; v.y = hv.y + o[i].y; v.z = hv.z + o[i].z; v.w = hv.w + o[i].w;
        float s1 = v.x + v.y + v.z + v.w;
        float s2 = v.x * v.x + v.y * v.y + v.z * v.z + v.w * v.w;
#pragma unroll
        for (int off = 16; off >= 1; off >>= 1) {
            s1 += __shfl_xor(s1, off);
            s2 += __shfl_xor(s2, off);
        }
        float mean = s1 * (1.f / HD);
        float var = s2 * (1.f / HD) - mean * mean;
        float rstd = rsqrtf(var + LNEPS);
        float4 y;
        y.x = (v.x - mean) * rstd * g4.x + lb4.x;
        y.y = (v.y - mean) * rstd * g4.y + lb4.y;
        y.z = (v.z - mean) * rstd * g4.z + lb4.z;
        y.w = (v.w - mean) * rstd * g4.w + lb4.w;
        if (r < NATOM) *(float4*)&h[(size_t)r * HD + c4] = y;
    }
}

// ======== fallback path (small ws): proven round-1 kernels ========
__global__ __launch_bounds__(256, 3) void edge_kernel_atomic(
    const float* __restrict__ edge_attr,
    const float* __restrict__ w1, const float* __restrict__ b1,
    const float* __restrict__ w2, const float* __restrict__ b2,
    const int* __restrict__ src, const int* __restrict__ dst,
    const float* __restrict__ h, float* __restrict__ agg)
{
    __shared__ float s_ea[64 * EFD];
    __shared__ float s_hid[64 * HD];
    __shared__ int s_src[64];
    __shared__ int s_dst[64];
    const int t = threadIdx.x, cg = t & 31, rg = t >> 5, c4 = cg * 4;

    float4 bb1 = *(const float4*)&b1[c4];
    float4 bb2 = *(const float4*)&b2[c4];

    const int ntiles = NEDGE / 64;
    for (int tile = blockIdx.x; tile < ntiles; tile += gridDim.x) {
        const int e0 = tile * 64;
        for (int i = t; i < 64 * EFD; i += 256) s_ea[i] = edge_attr[(size_t)e0 * EFD + i];
        if (t < 64) { s_src[t] = src[e0 + t]; s_dst[t] = dst[e0 + t]; }
        __syncthreads();
        float4 acc[8];
#pragma unroll
        for (int i = 0; i < 8; i++) acc[i] = bb1;
        for (int k = 0; k < EFD; k++) {
            float4 w = *(const float4*)&w1[k * HD + c4];
#pragma unroll
            for (int i = 0; i < 8; i++) {
                float a = s_ea[(rg * 8 + i) * EFD + k];
                acc[i].x += a * w.x; acc[i].y += a * w.y; acc[i].z += a * w.z; acc[i].w += a * w.w;
            }
        }
#pragma unroll
        for (int i = 0; i < 8; i++) {
            float4 v = acc[i];
            v.x = silu_f(v.x); v.y = silu_f(v.y); v.z = silu_f(v.z); v.w = silu_f(v.w);
            *(float4*)&s_hid[(rg * 8 + i) * HD + c4] = v;
        }
        __syncthreads();
        float4 o[8];
#pragma unroll
        for (int i = 0; i < 8; i++) o[i] = bb2;
        for (int j = 0; j < HD; j++) {
            float4 w = *(const float4*)&w2[j * HD + c4];
#pragma unroll
            for (int i = 0; i < 8; i++) {
                float a = s_hid[(rg * 8 + i) * HD + j];
                o[i].x += a * w.x; o[i].y += a * w.y; o[i].z += a * w.z; o[i].w += a * w.w;
            }
        }
#pragma unroll
        for (int i = 0; i < 8; i++) {
            int e = rg * 8 + i;
            int si = s_src[e], di = s_dst[e];
            float4 hs = *(const float4*)&h[(size_t)si * HD + c4];
            float* ap = agg + (size_t)di * HD + c4;
            atomicAdd(ap + 0, o[i].x * hs.x);
            atomicAdd(ap + 1, o[i].y * hs.y);
            atomicAdd(ap + 2, o[i].z * hs.z);
            atomicAdd(ap + 3, o[i].w * hs.w);
        }
        __syncthreads();
    }
}

__global__ __launch_bounds__(256, 2) void node_kernel_agg(
    const float* __restrict__ agg,
    const float* __restrict__ w1, const float* __restrict__ b1,
    const float* __restrict__ w2, const float* __restrict__ b2,
    const float* __restrict__ lg, const float* __restrict__ lb,
    float* __restrict__ h)
{
    __shared__ float s_in[64 * HD];
    __shared__ float s_hid[64 * HD];
    const int t = threadIdx.x, cg = t & 31, rg = t >> 5, c4 = cg * 4;
    const int r0 = blockIdx.x * 64;
    for (int i = t; i < 64 * HD; i += 256) {
        size_t g = (size_t)r0 * HD + i;
        s_in[i] = (g < (size_t)NATOM * HD) ? agg[g] : 0.f;
    }
    float4 bb1 = *(const float4*)&b1[c4];
    float4 bb2 = *(const float4*)&b2[c4];
    float4 g4 = *(const float4*)&lg[c4];
    float4 lb4 = *(const float4*)&lb[c4];
    __syncthreads();
    float4 acc[8];
#pragma unroll
    for (int i = 0; i < 8; i++) acc[i] = bb1;
    for (int k = 0; k < HD; k++) {
        float4 w = *(const float4*)&w1[k * HD + c4];
#pragma unroll
        for (int i = 0; i < 8; i++) {
            float a = s_in[(rg * 8 + i) * HD + k];
            acc[i].x += a * w.x; acc[i].y += a * w.y; acc[i].z += a * w.z; acc[i].w += a * w.w;
        }
    }
#pragma unroll
    for (int i = 0; i < 8; i++) {
        float4 v = acc[i];
        v.x = silu_f(v.x); v.y = silu_f(v.y); v.z = silu_f(v.z); v.w = silu_f(v.w);
        *(float4*)&s_hid[(rg * 8 + i) * HD + c4] = v;
    }
    __syncthreads();
    float4 o[8];
#pragma unroll
    for (int i = 0; i < 8; i++) o[i] = bb2;
    for (int j = 0; j < HD; j++) {
        float4 w = *(const float4*)&w2[j * HD + c4];
#pragma unroll
        for (int i = 0; i < 8; i++) {
            float a = s_hid[(rg * 8 + i) * HD + j];
            o[i].x += a * w.x; o[i].y += a * w.y; o[i].z += a * w.z; o[i].w += a * w.w;
        }
    }
#pragma unroll
    for (int i = 0; i < 8; i++) {
        int r = r0 + rg * 8 + i;
        float4 hv = make_float4(0.f, 0.f, 0.f, 0.f);
        if (r < NATOM) hv = *(const float4*)&h[(size_t)r * HD + c4];
        float4 v;
        v.x = hv.x + o[i].x; v.y = hv.y + o[i].y; v.z = hv.z + o[i].z; v.w = hv.w + o[i].w;
        float s1 = v.x + v.y + v.z + v.w;
        float s2 = v.x * v.x + v.y * v.y + v.z * v.z + v.w * v.w;
#pragma unroll
        for (int off = 16; off >= 1; off >>= 1) {
            s1 += __shfl_xor(s1, off);
            s2 += __shfl_xor(s2, off);
        }
        float mean = s1 * (1.f / HD);
        float var = s2 * (1.f / HD) - mean * mean;
        float rstd = rsqrtf(var + LNEPS);
        float4 y;
        y.x = (v.x - mean) * rstd * g4.x + lb4.x;
        y.y = (v.y - mean) * rstd * g4.y + lb4.y;
        y.z = (v.z - mean) * rstd * g4.z + lb4.z;
        y.w = (v.w - mean) * rstd * g4.w + lb4.w;
        if (r < NATOM) *(float4*)&h[(size_t)r * HD + c4] = y;
    }
}

// -------- pool + head: one block per graph ----------
__global__ __launch_bounds__(128) void head_kernel(
    const float* __restrict__ h, const float* __restrict__ gfeat,
    const float* __restrict__ gw, const float* __restrict__ gb,
    const float* __restrict__ ow1, const float* __restrict__ ob1,
    const float* __restrict__ ow2, const float* __restrict__ ob2,
    const float* __restrict__ ow3, const float* __restrict__ ob3,
    const int* __restrict__ batch, float* __restrict__ out)
{
    __shared__ float comb[2 * HD];
    __shared__ float h1[HD];
    __shared__ float h2[64];
    const int b = blockIdx.x;
    const int c = threadIdx.x;

    int lo = 0, hi = NATOM;
    while (lo < hi) { int m = (lo + hi) >> 1; if (batch[m] < b) lo = m + 1; else hi = m; }
    const int start = lo;
    hi = NATOM;
    while (lo < hi) { int m = (lo + hi) >> 1; if (batch[m] < b + 1) lo = m + 1; else hi = m; }
    const int end = lo;

    float s = 0.f;
    for (int r = start; r < end; r++) s += h[(size_t)r * HD + c];
    float cnt = (float)(end - start);
    if (cnt < 1.f) cnt = 1.f;
    comb[c] = s / cnt;

    float a = gb[c];
    for (int k = 0; k < GFD; k++) a += gfeat[b * GFD + k] * gw[k * HD + c];
    comb[HD + c] = silu_f(a);
    __syncthreads();

    float u = ob1[c];
    for (int j = 0; j < 2 * HD; j++) u += comb[j] * ow1[j * HD + c];
    h1[c] = silu_f(u);
    __syncthreads();

    if (c < 64) {
        float v = ob2[c];
        for (int j = 0; j < HD; j++) v += h1[j] * ow2[j * 64 + c];
        h2[c] = silu_f(v);
    }
    __syncthreads();

    if (c < TOUT) {
        float v = ob3[c];
        for (int j = 0; j < 64; j++) v += h2[j] * ow3[j * TOUT + c];
        out[b * TOUT + c] = v;
    }
}

extern "C" void kernel_launch(void* const* d_in, const int* in_sizes, int n_in,
                              void* d_out, int out_size, void* d_ws, size_t ws_size,
                              hipStream_t stream) {
    const float* x        = (const float*)d_in[0];
    const float* edge_attr= (const float*)d_in[1];
    const float* gfeat    = (const float*)d_in[2];
    const float* ae_w1    = (const float*)d_in[3];
    const float* ae_b1    = (const float*)d_in[4];
    const float* ae_w2    = (const float*)d_in[5];
    const float* ae_b2    = (const float*)d_in[6];
    const float* ew1      = (const float*)d_in[7];
    const float* eb1      = (const float*)d_in[8];
    const float* ew2      = (const float*)d_in[9];
    const float* eb2      = (const float*)d_in[10];
    const float* nw1      = (const float*)d_in[11];
    const float* nb1      = (const float*)d_in[12];
    const float* nw2      = (const float*)d_in[13];
    const float* nb2      = (const float*)d_in[14];
    const float* ln_g     = (const float*)d_in[15];
    const float* ln_b     = (const float*)d_in[16];
    const float* gw       = (const float*)d_in[17];
    const float* gb       = (const float*)d_in[18];
    const float* ow1      = (const float*)d_in[19];
    const float* ob1      = (const float*)d_in[20];
    const float* ow2      = (const float*)d_in[21];
    const float* ob2      = (const float*)d_in[22];
    const float* ow3      = (const float*)d_in[23];
    const float* ob3      = (const float*)d_in[24];
    const int* edge_index = (const int*)d_in[25];
    const int* batch      = (const int*)d_in[26];

    const int* src = edge_index;
    const int* dst = edge_index + NEDGE;
    const int row_blocks = (NATOM + 63) / 64;  // 782

    // primary-path workspace layout
    float* h    = (float*)d_ws;                           // NATOM*HD
    float* msg  = h + (size_t)NATOM * HD;                 // NEDGE*HD
    int* count  = (int*)(msg + (size_t)NEDGE * HD);       // NATOM
    int* rowptr = count + NATOM;                          // NATOM+1
    int* cursor = rowptr + NATOM + 1;                     // NATOM
    int* pos    = cursor + NATOM;                         // NEDGE
    size_t need = (size_t)(pos + NEDGE - (int*)d_ws) * sizeof(int);

    if (ws_size >= need) {
        // ---- primary: no atomics in hot path ----
        hipMemsetAsync(count, 0, NATOM * sizeof(int), stream);
        hist_kernel<<<1024, 256, 0, stream>>>(dst, count);
        scan_kernel<<<1, 256, 0, stream>>>(count, rowptr, cursor);
        pos_kernel<<<1024, 256, 0, stream>>>(dst, cursor, pos);

        atom_kernel<<<row_blocks, 256, 0, stream>>>(x, ae_w1, ae_b1, ae_w2, ae_b2, h);

        for (int l = 0; l < NL; l++) {
            edge_kernel_msg<<<2048, 256, 0, stream>>>(
                edge_attr,
                ew1 + (size_t)l * EFD * HD, eb1 + (size_t)l * HD,
                ew2 + (size_t)l * HD * HD,  eb2 + (size_t)l * HD,
                src, pos, h, msg);
            node_kernel_csr<<<row_blocks, 256, 0, stream>>>(
                msg, rowptr,
                nw1 + (size_t)l * HD * HD, nb1 + (size_t)l * HD,
                nw2 + (size_t)l * HD * HD, nb2 + (size_t)l * HD,
                ln_g + (size_t)l * HD, ln_b + (size_t)l * HD,
                h);
        }
    } else {
        // ---- fallback: atomic aggregation (round-1 proven path) ----
        float* agg = h + (size_t)NATOM * HD;
        atom_kernel<<<row_blocks, 256, 0, stream>>>(x, ae_w1, ae_b1, ae_w2, ae_b2, h);
        for (int l = 0; l < NL; l++) {
            hipMemsetAsync(agg, 0, (size_t)NATOM * HD * sizeof(float), stream);
            edge_kernel_atomic<<<2048, 256, 0, stream>>>(
                edge_attr,
                ew1 + (size_t)l * EFD * HD, eb1 + (size_t)l * HD,
                ew2 + (size_t)l * HD * HD,  eb2 + (size_t)l * HD,
                src, dst, h, agg);
            node_kernel_agg<<<row_blocks, 256, 0, stream>>>(
                agg,
                nw1 + (size_t)l * HD * HD, nb1 + (size_t)l * HD,
                nw2 + (size_t)l * HD * HD, nb2 + (size_t)l * HD,
                ln_g + (size_t)l * HD, ln_b + (size_t)l * HD,
                h);
        }
    }

    head_kernel<<<NGRAPH, 128, 0, stream>>>(
        h, gfeat, gw, gb, ow1, ob1, ow2, ob2, ow3, ob3, batch, (float*)d_out);
}